// Round 2
// baseline (63.199 us; speedup 1.0000x reference)
//
#include <hip/hip_runtime.h>

// out[o,h,w] = sum_i  (w>0) * x[i, (h-1)%14, (w-2)%14] * wt[o,0,i]
//            +        x[i, (h-1)%14, (w-1)%14] * wt[o,1,i]
//            + (w<13)* x[i, (h-1)%14,  w     ] * wt[o,2,i]
//
// x  : [128, 14, 14] f32
// wt : [32, 3, 128]  f32
// out: [32, 14, 14]  f32
//
// One block per output channel o (o uniform in block -> weight loads become
// scalar s_loads); one thread per (h,w); unroll-8 over input channels for
// memory-level parallelism. Problem is ~5 MFLOP / ~150 KB: latency-bound.

__global__ __launch_bounds__(256) void conv_roll_kernel(
    const float* __restrict__ x,
    const float* __restrict__ wt,
    float* __restrict__ out)
{
    const int o = blockIdx.x;        // 0..31
    const int t = threadIdx.x;       // 0..255, active < 196
    if (t >= 196) return;

    const int h  = t / 14;
    const int w  = t - h * 14;
    const int hh = (h + 13) % 14;    // undo output H-roll
    const int rb = hh * 14;

    // x column indices for the three taps (always in-bounds after mod)
    const int i0 = rb + ((w + 12) % 14);   // k=0 tap
    const int i1 = rb + ((w + 13) % 14);   // k=1 tap (always valid)
    const int i2 = rb + w;                 // k=2 tap

    const float m0 = (w > 0)  ? 1.0f : 0.0f;   // zero-pad mask, left edge
    const float m2 = (w < 13) ? 1.0f : 0.0f;   // zero-pad mask, right edge

    const float* __restrict__ wo = wt + o * 384;   // [3][128] for this o

    float a0 = 0.0f, a1 = 0.0f, a2 = 0.0f;
#pragma unroll 8
    for (int i = 0; i < 128; ++i) {
        const float* __restrict__ xp = x + i * 196;
        a0 = __builtin_fmaf(xp[i0], wo[i],       a0);
        a1 = __builtin_fmaf(xp[i1], wo[128 + i], a1);
        a2 = __builtin_fmaf(xp[i2], wo[256 + i], a2);
    }

    out[o * 196 + t] = m0 * a0 + a1 + m2 * a2;
}

extern "C" void kernel_launch(void* const* d_in, const int* in_sizes, int n_in,
                              void* d_out, int out_size, void* d_ws, size_t ws_size,
                              hipStream_t stream) {
    const float* x  = (const float*)d_in[0];   // 128*14*14 = 25088
    const float* wt = (const float*)d_in[1];   // 32*3*128  = 12288
    float* out = (float*)d_out;                // 32*14*14  = 6272

    conv_roll_kernel<<<32, 256, 0, stream>>>(x, wt, out);
}

// Round 3
// 56.014 us; speedup vs baseline: 1.1283x; 1.1283x over previous
//
#include <hip/hip_runtime.h>

// out[o,h,w] = sum_i  (w>0) * x[i, (h-1)%14, (w-2)%14] * wt[o,0,i]
//            +        x[i, (h-1)%14, (w-1)%14] * wt[o,1,i]
//            + (w<13)* x[i, (h-1)%14,  w     ] * wt[o,2,i]
//
// x  : [128, 14, 14] f32, wt : [32, 3, 128] f32, out: [32, 14, 14] f32
//
// Round 3: latency-bound fix. One block per (o, h) row -> 448 blocks
// (full CU coverage vs 32 before). 224 active threads = 16 channel-groups
// x 14 columns; each thread reduces only 8 channels x 3 taps = 24 loads,
// fully unrolled (one independent load batch instead of 16 serial ones).
// Partial sums reduced across channel-groups through LDS.

__global__ __launch_bounds__(256) void conv_roll_kernel(
    const float* __restrict__ x,
    const float* __restrict__ wt,
    float* __restrict__ out)
{
    __shared__ float red[224];   // [ci=16][w=14]

    const int bx = blockIdx.x;        // 0..447
    const int o  = bx / 14;           // 0..31 (uniform)
    const int h  = bx - o * 14;       // 0..13 (uniform)
    const int hh = (h + 13) % 14;     // undo output H-roll
    const int rb = hh * 14;

    const int t = threadIdx.x;        // 0..255, active < 224

    if (t < 224) {
        const int ci = t / 14;        // channel group 0..15
        const int w  = t - ci * 14;   // output column 0..13

        const int c0 = rb + ((w + 12) % 14);   // k=0 tap column
        const int c1 = rb + ((w + 13) % 14);   // k=1 tap (always valid)
        const int c2 = rb + w;                 // k=2 tap column

        const float* __restrict__ wo = wt + o * 384 + ci * 8;  // [3][8] slice
        const float* __restrict__ xb = x + (ci * 8) * 196;

        float a0 = 0.f, a1 = 0.f, a2 = 0.f;
#pragma unroll
        for (int j = 0; j < 8; ++j) {
            const float* __restrict__ xp = xb + j * 196;
            a0 = __builtin_fmaf(xp[c0], wo[j],       a0);
            a1 = __builtin_fmaf(xp[c1], wo[128 + j], a1);
            a2 = __builtin_fmaf(xp[c2], wo[256 + j], a2);
        }

        const float m0 = (w > 0)  ? 1.0f : 0.0f;   // left zero-pad mask
        const float m2 = (w < 13) ? 1.0f : 0.0f;   // right zero-pad mask
        red[t] = m0 * a0 + a1 + m2 * a2;
    }

    __syncthreads();

    if (t < 14) {
        float s = 0.f;
#pragma unroll
        for (int ci = 0; ci < 16; ++ci)
            s += red[ci * 14 + t];     // lanes read consecutive addrs per ci
        out[o * 196 + h * 14 + t] = s;
    }
}

extern "C" void kernel_launch(void* const* d_in, const int* in_sizes, int n_in,
                              void* d_out, int out_size, void* d_ws, size_t ws_size,
                              hipStream_t stream) {
    const float* x  = (const float*)d_in[0];   // 128*14*14 = 25088
    const float* wt = (const float*)d_in[1];   // 32*3*128  = 12288
    float* out = (float*)d_out;                // 32*14*14  = 6272

    conv_roll_kernel<<<448, 256, 0, stream>>>(x, wt, out);
}